// Round 6
// baseline (726.650 us; speedup 1.0000x reference)
//
#include <hip/hip_runtime.h>

// Problem constants (fixed by the reference setup).
#define BATCH  256
#define SEQT   2048
#define LAYERS 4
#define HID    64
#define CHUNK  16                        // timesteps per barrier phase
#define PHASES (SEQT / CHUNK + LAYERS - 1)
#define BPB    4                         // batches per block (4 chains/SIMD)
#define GRID   (BATCH / BPB)             // 64 blocks
#define NTHR   (BPB * LAYERS * 64)       // 1024 threads / 16 waves
// P (input / projected hidden size) == 1

#define LOG2E  1.4426950408889634f
#define K2     (2.0f * LOG2E)            // c is carried as C = K2 * c

__device__ __forceinline__ float fast_rcp(float x) {
    return __builtin_amdgcn_rcpf(x);
}
__device__ __forceinline__ float fast_exp2(float x) {
    return __builtin_amdgcn_exp2f(x);    // raw v_exp_f32 (2^x)
}

// One DPP-shifted add: v += dpp_move(v). bound_ctrl=true -> invalid lanes read 0.
#define DPP_ADD(v, ctrl)                                                     \
    (v) += __int_as_float(__builtin_amdgcn_update_dpp(                       \
        0, __float_as_int(v), (ctrl), 0xF, 0xF, true))

// Full wave64 sum via DPP row reduce + row broadcasts; total lands in lane 63.
__device__ __forceinline__ float wave_sum_lane63(float v) {
    DPP_ADD(v, 0x111);   // row_shr:1
    DPP_ADD(v, 0x112);   // row_shr:2
    DPP_ADD(v, 0x114);   // row_shr:4
    DPP_ADD(v, 0x118);   // row_shr:8 -> lanes 15/31/47/63 = row sums
    DPP_ADD(v, 0x142);   // row_bcast:15
    DPP_ADD(v, 0x143);   // row_bcast:31 -> lane 63 = full sum
    return v;
}

// 4 batches x 4 layers = 16 waves per block; wave w: batch-in-block = w>>2,
// layer = w&3, lane k = hidden unit. Each SIMD hosts ~4 waves with INDEPENDENT
// recurrence chains, so chain-latency stalls of one wave are filled by the
// others (the round-5 kernel had 1 wave/SIMD and ran at chain latency).
// Software pipeline across time in CHUNK-step phases as before; inter-layer h
// through double-buffered LDS; outputs LDS-buffered, flushed once; layer-0
// inputs register-prefetched one phase ahead from global (wave-uniform float4
// loads, L1-resident -- y_lds staging dropped to fit the 64 KB LDS budget).
__global__ __launch_bounds__(NTHR, 4) void lstm_pipeline_kernel(
    const float* __restrict__ y,      // [B, T, 1]
    const float* __restrict__ W_ih,   // [L, 4H, 1]
    const float* __restrict__ W_hh,   // [L, 4H, 1]
    const float* __restrict__ b_ih,   // [L, 4H]
    const float* __restrict__ b_hh,   // [L, 4H]
    const float* __restrict__ W_hr,   // [L, 1, H]
    const int*  __restrict__ msl_p,   // min_seq_len scalar
    float* __restrict__ out)          // [B, T - msl, 1]
{
    const int tid = threadIdx.x;
    const int w   = tid >> 6;
    const int bi  = w >> 2;     // batch within block
    const int l   = w & 3;      // layer
    const int k   = tid & 63;   // hidden unit / lane
    const int b   = blockIdx.x * BPB + bi;
    const int msl = *msl_p;

    __shared__ float out_lds[BPB][SEQT];                            // 32 KB
    __shared__ __align__(16) float h_buf[2][BPB][LAYERS][CHUNK];    //  2 KB

    // Loop-invariant weights. Gate order: i, f, g, o.
    // i, f, o carry -log2e (exp2 -> e^-gate); g carries 2*log2e.
    const int wbase = l * 4 * HID;
    const float wi0 = -LOG2E * W_ih[wbase + 0 * HID + k];
    const float wi1 = -LOG2E * W_ih[wbase + 1 * HID + k];
    const float wi2 =  K2    * W_ih[wbase + 2 * HID + k];
    const float wi3 = -LOG2E * W_ih[wbase + 3 * HID + k];
    const float wh0 = -LOG2E * W_hh[wbase + 0 * HID + k];
    const float wh1 = -LOG2E * W_hh[wbase + 1 * HID + k];
    const float wh2 =  K2    * W_hh[wbase + 2 * HID + k];
    const float wh3 = -LOG2E * W_hh[wbase + 3 * HID + k];
    const float bb0 = -LOG2E * (b_ih[wbase + 0 * HID + k] + b_hh[wbase + 0 * HID + k]);
    const float bb1 = -LOG2E * (b_ih[wbase + 1 * HID + k] + b_hh[wbase + 1 * HID + k]);
    const float bb2 =  K2    * (b_ih[wbase + 2 * HID + k] + b_hh[wbase + 2 * HID + k]);
    const float bb3 = -LOG2E * (b_ih[wbase + 3 * HID + k] + b_hh[wbase + 3 * HID + k]);
    const float wr  = W_hr[l * HID + k];

    float h = 0.0f;   // projected hidden (wave-uniform)
    float C = 0.0f;   // cell state, scaled: C = 2*log2e*c

    // Layer-0 input prefetch registers (one phase ahead).
    const float4* yb = (const float4*)(y + (size_t)b * SEQT);
    float4 xpre[CHUNK / 4];
    if (l == 0) {
        #pragma unroll
        for (int q = 0; q < CHUNK / 4; ++q) xpre[q] = yb[q];   // phase 0
    }

    for (int p = 0; p < PHASES; ++p) {
        __syncthreads();   // publishes previous phase's h_buf writes (LDS only)
        const int t0 = (p - l) * CHUNK;
        if (t0 >= 0 && t0 < SEQT) {
            // This chunk's 16 scalar inputs (wave-uniform).
            float4 xv[CHUNK / 4];
            if (l == 0) {
                #pragma unroll
                for (int q = 0; q < CHUNK / 4; ++q) xv[q] = xpre[q];
                if (t0 + CHUNK < SEQT) {       // prefetch next phase
                    #pragma unroll
                    for (int q = 0; q < CHUNK / 4; ++q)
                        xpre[q] = yb[(t0 + CHUNK) / 4 + q];
                }
            } else {
                const float4* hb = (const float4*)&h_buf[(p - 1) & 1][bi][l - 1][0];
                #pragma unroll
                for (int q = 0; q < CHUNK / 4; ++q) xv[q] = hb[q];
            }
            float xs[CHUNK];
            #pragma unroll
            for (int q = 0; q < CHUNK / 4; ++q) {
                xs[4 * q + 0] = xv[q].x; xs[4 * q + 1] = xv[q].y;
                xs[4 * q + 2] = xv[q].z; xs[4 * q + 3] = xv[q].w;
            }

            // Input-side gate contributions: independent of h, off the chain.
            float p0[CHUNK], p1[CHUNK], p2[CHUNK], p3[CHUNK];
            #pragma unroll
            for (int j = 0; j < CHUNK; ++j) {
                p0[j] = fmaf(xs[j], wi0, bb0);
                p1[j] = fmaf(xs[j], wi1, bb1);
                p2[j] = fmaf(xs[j], wi2, bb2);
                p3[j] = fmaf(xs[j], wi3, bb3);
            }

            #pragma unroll
            for (int j = 0; j < CHUNK; ++j) {
                // Gate pre-activations (scale factors pre-folded into weights).
                const float gi = fmaf(h, wh0, p0[j]);
                const float gf = fmaf(h, wh1, p1[j]);
                const float gg = fmaf(h, wh2, p2[j]);
                const float go = fmaf(h, wh3, p3[j]);

                const float Ei = fast_exp2(gi);     // e^-i
                const float Ef = fast_exp2(gf);     // e^-f
                const float Eg = fast_exp2(gg);     // e^{2g}
                const float Eo = fast_exp2(go);     // e^-o

                // sf = sigmoid(f)
                const float sf = fast_rcp(1.0f + Ef);

                // si * tanh(g) * K2, single reciprocal.
                const float num_g  = fmaf(K2, Eg, -K2);             // K2(Eg-1)
                const float den_ig = (1.0f + Ei) * (1.0f + Eg);
                const float si_tgK = num_g * fast_rcp(den_ig);

                C = fmaf(sf, C, si_tgK);

                // v = so * tanh(c) * wr, single reciprocal.
                const float Ec     = fast_exp2(C);                  // e^{2c}
                const float num_o  = fmaf(wr, Ec, -wr);             // wr(Ec-1)
                const float den_oc = (1.0f + Eo) * (1.0f + Ec);
                const float v      = num_o * fast_rcp(den_oc);

                const float vs = wave_sum_lane63(v);      // lane 63 = sum

                if (k == 63) {
                    if (l < LAYERS - 1) h_buf[p & 1][bi][l][j] = vs; // next layer
                    else                out_lds[bi][t0 + j] = vs;    // output
                }
                // Broadcast for this wave's own next step.
                h = __int_as_float(
                    __builtin_amdgcn_readlane(__float_as_int(vs), 63));
            }
        }
    }

    // Flush buffered outputs to global once (coalesced per 256-thread group).
    __syncthreads();
    const int nout = SEQT - msl;
    const int fb   = tid >> 8;            // batch within block
    const int ft   = tid & 255;
    float* outb = out + (size_t)(blockIdx.x * BPB + fb) * nout;
    for (int i = ft; i < nout; i += 256) outb[i] = out_lds[fb][i + msl];
}

extern "C" void kernel_launch(void* const* d_in, const int* in_sizes, int n_in,
                              void* d_out, int out_size, void* d_ws, size_t ws_size,
                              hipStream_t stream) {
    const float* y    = (const float*)d_in[0];
    const float* W_ih = (const float*)d_in[1];
    const float* W_hh = (const float*)d_in[2];
    const float* b_ih = (const float*)d_in[3];
    const float* b_hh = (const float*)d_in[4];
    const float* W_hr = (const float*)d_in[5];
    const int*   msl  = (const int*)d_in[6];
    float* out = (float*)d_out;

    lstm_pipeline_kernel<<<GRID, NTHR, 0, stream>>>(
        y, W_ih, W_hh, b_ih, b_hh, W_hr, msl, out);
}

// Round 7
// 331.769 us; speedup vs baseline: 2.1902x; 2.1902x over previous
//
#include <hip/hip_runtime.h>

// Problem constants (fixed by the reference setup).
#define BATCH  256
#define SEQT   2048
#define LAYERS 4
#define HID    64
#define CHUNK  16                        // timesteps per barrier phase
#define PHASES (SEQT / CHUNK + LAYERS - 1)
// P (input / projected hidden size) == 1

#define LOG2E  1.4426950408889634f
#define K2     (2.0f * LOG2E)            // c is carried as C = K2 * c

__device__ __forceinline__ float fast_rcp(float x) {
    return __builtin_amdgcn_rcpf(x);
}
__device__ __forceinline__ float fast_exp2(float x) {
    return __builtin_amdgcn_exp2f(x);    // raw v_exp_f32 (2^x)
}

// One DPP-shifted add: v += dpp_move(v). bound_ctrl=true -> invalid lanes read 0.
#define DPP_ADD(v, ctrl)                                                     \
    (v) += __int_as_float(__builtin_amdgcn_update_dpp(                       \
        0, __float_as_int(v), (ctrl), 0xF, 0xF, true))

// Full wave64 sum via DPP row reduce + row broadcasts; total lands in lane 63.
__device__ __forceinline__ float wave_sum_lane63(float v) {
    DPP_ADD(v, 0x111);   // row_shr:1
    DPP_ADD(v, 0x112);   // row_shr:2
    DPP_ADD(v, 0x114);   // row_shr:4
    DPP_ADD(v, 0x118);   // row_shr:8 -> lanes 15/31/47/63 = row sums
    DPP_ADD(v, 0x142);   // row_bcast:15
    DPP_ADD(v, 0x143);   // row_bcast:31 -> lane 63 = full sum
    return v;
}

// One block per batch element, 4 waves = 4 layers (1 wave/SIMD -- measured
// optimum: round-6 showed issue ~192 cy/step, so packing >=2 chains/SIMD costs
// more than the 330 cy latency-bound wall). Software pipeline across time in
// CHUNK-step phases; inter-layer h via double-buffered LDS; outputs
// LDS-buffered, flushed once. 7 transcendentals/step: 5 exp2 + 2 rcp.
// c-update uses ONE merged reciprocal:
//   sf*C + si*tanh(g)*K2 = [C(1+Ei)(1+Eg) + K2(Eg-1)(1+Ef)]
//                          / [(1+Ef)(1+Ei)(1+Eg)]
// output uses one:  v = wr(Ec-1) / ((1+Eo)(1+Ec)),  Ec = e^{2c}.
__global__ __launch_bounds__(256, 1) void lstm_pipeline_kernel(
    const float* __restrict__ y,      // [B, T, 1]
    const float* __restrict__ W_ih,   // [L, 4H, 1]
    const float* __restrict__ W_hh,   // [L, 4H, 1]
    const float* __restrict__ b_ih,   // [L, 4H]
    const float* __restrict__ b_hh,   // [L, 4H]
    const float* __restrict__ W_hr,   // [L, 1, H]
    const int*  __restrict__ msl_p,   // min_seq_len scalar
    float* __restrict__ out)          // [B, T - msl, 1]
{
    const int b   = blockIdx.x;
    const int tid = threadIdx.x;
    const int l   = tid >> 6;   // layer / wave id
    const int k   = tid & 63;   // hidden unit / lane
    const int msl = *msl_p;

    __shared__ float y_lds[SEQT];                              // 8 KB
    __shared__ float out_lds[SEQT];                            // 8 KB
    __shared__ __align__(16) float h_buf[2][LAYERS][CHUNK];    // inter-layer h

    // Stage y[b, :] into LDS with float4 loads.
    {
        const float4* y4  = (const float4*)(y + (size_t)b * SEQT);
        float4*       yl4 = (float4*)y_lds;
        #pragma unroll
        for (int i = tid; i < SEQT / 4; i += 256) yl4[i] = y4[i];
    }

    // Loop-invariant weights. Gate order: i, f, g, o.
    // i, f, o carry -log2e (exp2 -> e^-gate); g carries 2*log2e (exp2 -> e^{2g}).
    const int wbase = l * 4 * HID;
    const float wi0 = -LOG2E * W_ih[wbase + 0 * HID + k];
    const float wi1 = -LOG2E * W_ih[wbase + 1 * HID + k];
    const float wi2 =  K2    * W_ih[wbase + 2 * HID + k];
    const float wi3 = -LOG2E * W_ih[wbase + 3 * HID + k];
    const float wh0 = -LOG2E * W_hh[wbase + 0 * HID + k];
    const float wh1 = -LOG2E * W_hh[wbase + 1 * HID + k];
    const float wh2 =  K2    * W_hh[wbase + 2 * HID + k];
    const float wh3 = -LOG2E * W_hh[wbase + 3 * HID + k];
    const float bb0 = -LOG2E * (b_ih[wbase + 0 * HID + k] + b_hh[wbase + 0 * HID + k]);
    const float bb1 = -LOG2E * (b_ih[wbase + 1 * HID + k] + b_hh[wbase + 1 * HID + k]);
    const float bb2 =  K2    * (b_ih[wbase + 2 * HID + k] + b_hh[wbase + 2 * HID + k]);
    const float bb3 = -LOG2E * (b_ih[wbase + 3 * HID + k] + b_hh[wbase + 3 * HID + k]);
    const float wr  = W_hr[l * HID + k];

    float h = 0.0f;   // projected hidden (wave-uniform)
    float C = 0.0f;   // cell state, scaled: C = 2*log2e*c

    for (int p = 0; p < PHASES; ++p) {
        __syncthreads();   // publishes previous phase's h_buf writes (LDS only)
        const int t0 = (p - l) * CHUNK;
        if (t0 >= 0 && t0 < SEQT) {
            // Fetch this chunk's 16 scalar inputs (wave-uniform broadcast reads).
            float4 xv[CHUNK / 4];
            if (l == 0) {
                const float4* ys = (const float4*)&y_lds[t0];
                #pragma unroll
                for (int q = 0; q < CHUNK / 4; ++q) xv[q] = ys[q];
            } else {
                const float4* hb = (const float4*)&h_buf[(p - 1) & 1][l - 1][0];
                #pragma unroll
                for (int q = 0; q < CHUNK / 4; ++q) xv[q] = hb[q];
            }
            float xs[CHUNK];
            #pragma unroll
            for (int q = 0; q < CHUNK / 4; ++q) {
                xs[4 * q + 0] = xv[q].x; xs[4 * q + 1] = xv[q].y;
                xs[4 * q + 2] = xv[q].z; xs[4 * q + 3] = xv[q].w;
            }

            // Input-side gate contributions: independent of h, off the chain.
            float p0[CHUNK], p1[CHUNK], p2[CHUNK], p3[CHUNK];
            #pragma unroll
            for (int j = 0; j < CHUNK; ++j) {
                p0[j] = fmaf(xs[j], wi0, bb0);
                p1[j] = fmaf(xs[j], wi1, bb1);
                p2[j] = fmaf(xs[j], wi2, bb2);
                p3[j] = fmaf(xs[j], wi3, bb3);
            }

            #pragma unroll
            for (int j = 0; j < CHUNK; ++j) {
                // Gate pre-activations (scale factors pre-folded into weights).
                const float gi = fmaf(h, wh0, p0[j]);
                const float gf = fmaf(h, wh1, p1[j]);
                const float gg = fmaf(h, wh2, p2[j]);
                const float go = fmaf(h, wh3, p3[j]);

                const float Ei = fast_exp2(gi);     // e^-i
                const float Ef = fast_exp2(gf);     // e^-f
                const float Eg = fast_exp2(gg);     // e^{2g}
                const float Eo = fast_exp2(go);     // e^-o

                // Merged c-update: one reciprocal for sf*C + si*tanh(g)*K2.
                const float ai     = 1.0f + Ei;
                const float ag     = 1.0f + Eg;
                const float af     = 1.0f + Ef;
                const float den_ig = ai * ag;
                const float tg     = fmaf(K2, Eg, -K2);   // K2(Eg-1)
                const float tgf    = tg * af;             // K2(Eg-1)(1+Ef)
                const float num    = fmaf(C, den_ig, tgf);
                const float den    = den_ig * af;
                C = num * fast_rcp(den);

                // Output: v = wr(Ec-1)/((1+Eo)(1+Ec)), one reciprocal.
                const float Ec   = fast_exp2(C);          // e^{2c}
                const float ao   = 1.0f + Eo;
                const float ac   = 1.0f + Ec;
                const float den2 = ao * ac;
                const float num2 = fmaf(wr, Ec, -wr);     // wr(Ec-1)
                const float v    = num2 * fast_rcp(den2);

                const float vs = wave_sum_lane63(v);      // lane 63 = sum

                if (k == 63) {
                    if (l < LAYERS - 1) h_buf[p & 1][l][j] = vs;  // next layer
                    else                out_lds[t0 + j]   = vs;   // final output
                }
                // Broadcast for this wave's own next step.
                h = __int_as_float(
                    __builtin_amdgcn_readlane(__float_as_int(vs), 63));
            }
        }
    }

    // Flush buffered outputs to global once (coalesced).
    __syncthreads();
    const int nout = SEQT - msl;
    float* outb = out + (size_t)b * nout;
    for (int i = tid; i < nout; i += 256) outb[i] = out_lds[i + msl];
}

extern "C" void kernel_launch(void* const* d_in, const int* in_sizes, int n_in,
                              void* d_out, int out_size, void* d_ws, size_t ws_size,
                              hipStream_t stream) {
    const float* y    = (const float*)d_in[0];
    const float* W_ih = (const float*)d_in[1];
    const float* W_hh = (const float*)d_in[2];
    const float* b_ih = (const float*)d_in[3];
    const float* b_hh = (const float*)d_in[4];
    const float* W_hr = (const float*)d_in[5];
    const int*   msl  = (const int*)d_in[6];
    float* out = (float*)d_out;

    lstm_pipeline_kernel<<<BATCH, 256, 0, stream>>>(
        y, W_ih, W_hh, b_ih, b_hh, W_hr, msl, out);
}

// Round 9
// 319.701 us; speedup vs baseline: 2.2729x; 1.0377x over previous
//
#include <hip/hip_runtime.h>

// Problem constants (fixed by the reference setup).
#define BATCH  256
#define SEQT   2048
#define LAYERS 4
#define HID    64
#define CHUNK  16                        // timesteps per barrier phase
#define PHASES (SEQT / CHUNK + LAYERS - 1)
// P (input / projected hidden size) == 1

#define LOG2E  1.4426950408889634f
#define K2     (2.0f * LOG2E)            // c is carried as C = K2 * c

__device__ __forceinline__ float fast_rcp(float x) {
    return __builtin_amdgcn_rcpf(x);
}
__device__ __forceinline__ float fast_exp2(float x) {
    return __builtin_amdgcn_exp2f(x);    // raw v_exp_f32 (2^x)
}

// One DPP-shifted add: v += dpp_move(v). bound_ctrl=true -> invalid lanes read 0.
#define DPP_ADD(v, ctrl)                                                     \
    (v) += __int_as_float(__builtin_amdgcn_update_dpp(                       \
        0, __float_as_int(v), (ctrl), 0xF, 0xF, true))

// Full wave64 sum via DPP row reduce + row broadcasts; total lands in lane 63.
__device__ __forceinline__ float wave_sum_lane63(float v) {
    DPP_ADD(v, 0x111);   // row_shr:1
    DPP_ADD(v, 0x112);   // row_shr:2
    DPP_ADD(v, 0x114);   // row_shr:4
    DPP_ADD(v, 0x118);   // row_shr:8 -> lanes 15/31/47/63 = row sums
    DPP_ADD(v, 0x142);   // row_bcast:15
    DPP_ADD(v, 0x143);   // row_bcast:31 -> lane 63 = full sum
    return v;
}

// One block per batch element, 4 waves = 4 layers (1 wave/SIMD -- measured
// optimum; round-6 showed SIMD-sharing costs more than it hides). Software
// pipeline across time in CHUNK-step phases; inter-layer h via double-buffered
// LDS; outputs LDS-buffered, flushed once. 7 transcendentals/step.
//
// Phase body is ONE basic block: per-step h values are collected into a
// lane-indexed VGPR with a branch-free select (v_cmp + v_cndmask; exec-safe,
// no basic-block split) and stored to LDS ONCE per phase by lanes 0..15 --
// the per-step `if (k==63)` stores of earlier rounds broke the unrolled chunk
// into 16 basic blocks and blocked the scheduler from filling chain-latency
// stalls with off-chain work (precompute fmas, unpacks).
__global__ __launch_bounds__(256, 1) void lstm_pipeline_kernel(
    const float* __restrict__ y,      // [B, T, 1]
    const float* __restrict__ W_ih,   // [L, 4H, 1]
    const float* __restrict__ W_hh,   // [L, 4H, 1]
    const float* __restrict__ b_ih,   // [L, 4H]
    const float* __restrict__ b_hh,   // [L, 4H]
    const float* __restrict__ W_hr,   // [L, 1, H]
    const int*  __restrict__ msl_p,   // min_seq_len scalar
    float* __restrict__ out)          // [B, T - msl, 1]
{
    const int b   = blockIdx.x;
    const int tid = threadIdx.x;
    const int l   = tid >> 6;   // layer / wave id
    const int k   = tid & 63;   // hidden unit / lane
    const int msl = *msl_p;

    __shared__ float y_lds[SEQT];                              // 8 KB
    __shared__ float out_lds[SEQT];                            // 8 KB
    __shared__ __align__(16) float h_buf[2][LAYERS][CHUNK];    // inter-layer h

    // Stage y[b, :] into LDS with float4 loads.
    {
        const float4* y4  = (const float4*)(y + (size_t)b * SEQT);
        float4*       yl4 = (float4*)y_lds;
        #pragma unroll
        for (int i = tid; i < SEQT / 4; i += 256) yl4[i] = y4[i];
    }

    // Loop-invariant weights. Gate order: i, f, g, o.
    // i, f, o carry -log2e (exp2 -> e^-gate); g carries 2*log2e (exp2 -> e^{2g}).
    const int wbase = l * 4 * HID;
    const float wi0 = -LOG2E * W_ih[wbase + 0 * HID + k];
    const float wi1 = -LOG2E * W_ih[wbase + 1 * HID + k];
    const float wi2 =  K2    * W_ih[wbase + 2 * HID + k];
    const float wi3 = -LOG2E * W_ih[wbase + 3 * HID + k];
    const float wh0 = -LOG2E * W_hh[wbase + 0 * HID + k];
    const float wh1 = -LOG2E * W_hh[wbase + 1 * HID + k];
    const float wh2 =  K2    * W_hh[wbase + 2 * HID + k];
    const float wh3 = -LOG2E * W_hh[wbase + 3 * HID + k];
    const float bb0 = -LOG2E * (b_ih[wbase + 0 * HID + k] + b_hh[wbase + 0 * HID + k]);
    const float bb1 = -LOG2E * (b_ih[wbase + 1 * HID + k] + b_hh[wbase + 1 * HID + k]);
    const float bb2 =  K2    * (b_ih[wbase + 2 * HID + k] + b_hh[wbase + 2 * HID + k]);
    const float bb3 = -LOG2E * (b_ih[wbase + 3 * HID + k] + b_hh[wbase + 3 * HID + k]);
    const float wr  = W_hr[l * HID + k];

    float h = 0.0f;   // projected hidden (wave-uniform)
    float C = 0.0f;   // cell state, scaled: C = 2*log2e*c

    for (int p = 0; p < PHASES; ++p) {
        __syncthreads();   // publishes previous phase's h_buf writes (LDS only)
        const int t0 = (p - l) * CHUNK;
        if (t0 >= 0 && t0 < SEQT) {
            // Fetch this chunk's 16 scalar inputs (wave-uniform broadcast reads).
            float4 xv[CHUNK / 4];
            if (l == 0) {
                const float4* ys = (const float4*)&y_lds[t0];
                #pragma unroll
                for (int q = 0; q < CHUNK / 4; ++q) xv[q] = ys[q];
            } else {
                const float4* hb = (const float4*)&h_buf[(p - 1) & 1][l - 1][0];
                #pragma unroll
                for (int q = 0; q < CHUNK / 4; ++q) xv[q] = hb[q];
            }
            float xs[CHUNK];
            #pragma unroll
            for (int q = 0; q < CHUNK / 4; ++q) {
                xs[4 * q + 0] = xv[q].x; xs[4 * q + 1] = xv[q].y;
                xs[4 * q + 2] = xv[q].z; xs[4 * q + 3] = xv[q].w;
            }

            // Input-side gate contributions: independent of h, off the chain.
            float p0[CHUNK], p1[CHUNK], p2[CHUNK], p3[CHUNK];
            #pragma unroll
            for (int j = 0; j < CHUNK; ++j) {
                p0[j] = fmaf(xs[j], wi0, bb0);
                p1[j] = fmaf(xs[j], wi1, bb1);
                p2[j] = fmaf(xs[j], wi2, bb2);
                p3[j] = fmaf(xs[j], wi3, bb3);
            }

            // Collector: lane j ends up holding step j's h (branch-free select;
            // 2 off-chain VALU ops per step, zero critical-path cost).
            float hcol = 0.0f;

            #pragma unroll
            for (int j = 0; j < CHUNK; ++j) {
                // Gate pre-activations (scale factors pre-folded into weights).
                const float gi = fmaf(h, wh0, p0[j]);
                const float gf = fmaf(h, wh1, p1[j]);
                const float gg = fmaf(h, wh2, p2[j]);
                const float go = fmaf(h, wh3, p3[j]);

                const float Ei = fast_exp2(gi);     // e^-i
                const float Ef = fast_exp2(gf);     // e^-f
                const float Eg = fast_exp2(gg);     // e^{2g}
                const float Eo = fast_exp2(go);     // e^-o

                // Merged c-update: one reciprocal for sf*C + si*tanh(g)*K2.
                const float ai     = 1.0f + Ei;
                const float ag     = 1.0f + Eg;
                const float af     = 1.0f + Ef;
                const float den_ig = ai * ag;
                const float tg     = fmaf(K2, Eg, -K2);   // K2(Eg-1)
                const float tgf    = tg * af;             // K2(Eg-1)(1+Ef)
                const float num    = fmaf(C, den_ig, tgf);
                const float den    = den_ig * af;
                C = num * fast_rcp(den);

                // Output: v = wr(Ec-1)/((1+Eo)(1+Ec)), one reciprocal.
                const float Ec   = fast_exp2(C);          // e^{2c}
                const float ao   = 1.0f + Eo;
                const float ac   = 1.0f + Ec;
                const float den2 = ao * ac;
                const float num2 = fmaf(wr, Ec, -wr);     // wr(Ec-1)
                const float v    = num2 * fast_rcp(den2);

                const float vs = wave_sum_lane63(v);      // lane 63 = sum

                // Wave-uniform h for the next step (readlane -> SGPR).
                h = __int_as_float(
                    __builtin_amdgcn_readlane(__float_as_int(vs), 63));

                // Deposit into lane j of the collector -- no branch.
                hcol = (k == j) ? h : hcol;
            }

            // One masked LDS store per phase (lanes 0..15 hold steps 0..15).
            if (k < CHUNK) {
                if (l < LAYERS - 1) h_buf[p & 1][l][k] = hcol;
                else                out_lds[t0 + k]    = hcol;
            }
        }
    }

    // Flush buffered outputs to global once (coalesced).
    __syncthreads();
    const int nout = SEQT - msl;
    float* outb = out + (size_t)b * nout;
    for (int i = tid; i < nout; i += 256) outb[i] = out_lds[i + msl];
}

extern "C" void kernel_launch(void* const* d_in, const int* in_sizes, int n_in,
                              void* d_out, int out_size, void* d_ws, size_t ws_size,
                              hipStream_t stream) {
    const float* y    = (const float*)d_in[0];
    const float* W_ih = (const float*)d_in[1];
    const float* W_hh = (const float*)d_in[2];
    const float* b_ih = (const float*)d_in[3];
    const float* b_hh = (const float*)d_in[4];
    const float* W_hr = (const float*)d_in[5];
    const int*   msl  = (const int*)d_in[6];
    float* out = (float*)d_out;

    lstm_pipeline_kernel<<<BATCH, 256, 0, stream>>>(
        y, W_ih, W_hh, b_ih, b_hh, W_hr, msl, out);
}